// Round 3
// baseline (306.405 us; speedup 1.0000x reference)
//
#include <hip/hip_runtime.h>

#define D 64
#define SCAN_CHUNK 1024   // elements per scan1 block (256 thr x 4)

// ---------------- tap0: y[row][j] = sum_i xin[row][i]*W[j][i] + b[j] -------
__global__ __launch_bounds__(256) void tap_kernel(
    const float* __restrict__ xin, const float* __restrict__ W,
    const float* __restrict__ b, float* __restrict__ y,
    int n_nodes, int first)
{
    __shared__ float Wt[D * (D + 1)];
    __shared__ float bs[D];
    __shared__ float xs[4][D];

    int tid = threadIdx.x;
    for (int t = tid; t < D * D; t += 256) {
        int j = t >> 6, i = t & 63;
        Wt[i * (D + 1) + j] = W[t];
    }
    if (tid < D) bs[tid] = b[tid];

    int rl = tid >> 6;
    int j  = tid & 63;
    int row = blockIdx.x * 4 + rl;
    if (row < n_nodes) xs[rl][j] = xin[row * D + j];
    __syncthreads();

    if (row >= n_nodes) return;

    float acc = bs[j];
    #pragma unroll 8
    for (int i = 0; i < D; ++i)
        acc = fmaf(xs[rl][i], Wt[i * (D + 1) + j], acc);

    float* yp = y + (size_t)row * D + j;
    *yp = first ? acc : (*yp + acc);
}

// ---------------- CSR build ------------------------------------------------
// pass 1: histogram of dst + per-edge local offset (slot within node)
__global__ __launch_bounds__(256) void hist_loc_kernel(
    const int* __restrict__ dst, int* __restrict__ counts,
    int* __restrict__ loc, int n_edges)
{
    int t = blockIdx.x * 256 + threadIdx.x;
    int e4 = t * 4;
    if (e4 + 4 <= n_edges) {
        int4 d = *reinterpret_cast<const int4*>(dst + e4);
        int4 l;
        l.x = atomicAdd(&counts[d.x], 1);
        l.y = atomicAdd(&counts[d.y], 1);
        l.z = atomicAdd(&counts[d.z], 1);
        l.w = atomicAdd(&counts[d.w], 1);
        *reinterpret_cast<int4*>(loc + e4) = l;
    } else {
        for (int e = e4; e < n_edges; ++e)
            loc[e] = atomicAdd(&counts[dst[e]], 1);
    }
}

// per-block (1024-elem chunk) exclusive scan; block totals to bsum
__global__ __launch_bounds__(256) void scan1_kernel(
    const int* __restrict__ counts, int* __restrict__ excl,
    int* __restrict__ bsum, int n)
{
    __shared__ int lds[256];
    int tid = threadIdx.x;
    int base = blockIdx.x * SCAN_CHUNK + tid * 4;
    int c0 = 0, c1 = 0, c2 = 0, c3 = 0;
    if (base + 3 < n) {
        int4 v = *reinterpret_cast<const int4*>(counts + base);
        c0 = v.x; c1 = v.y; c2 = v.z; c3 = v.w;
    } else {
        if (base + 0 < n) c0 = counts[base + 0];
        if (base + 1 < n) c1 = counts[base + 1];
        if (base + 2 < n) c2 = counts[base + 2];
        if (base + 3 < n) c3 = counts[base + 3];
    }
    int s = c0 + c1 + c2 + c3;
    lds[tid] = s;
    __syncthreads();
    for (int off = 1; off < 256; off <<= 1) {
        int v = (tid >= off) ? lds[tid - off] : 0;
        __syncthreads();
        lds[tid] += v;
        __syncthreads();
    }
    int incl = lds[tid];
    int ex = incl - s;
    if (tid == 255) bsum[blockIdx.x] = incl;
    if (base + 0 < n) excl[base + 0] = ex;
    if (base + 1 < n) excl[base + 1] = ex + c0;
    if (base + 2 < n) excl[base + 2] = ex + c0 + c1;
    if (base + 3 < n) excl[base + 3] = ex + c0 + c1 + c2;
}

// exclusive scan of block sums (nb <= 64), single wave
__global__ __launch_bounds__(64) void scan2_kernel(int* __restrict__ bsum, int nb)
{
    int lane = threadIdx.x;
    int v = (lane < nb) ? bsum[lane] : 0;
    int orig = v;
    for (int off = 1; off < 64; off <<= 1) {
        int t = __shfl_up(v, off);
        if (lane >= off) v += t;
    }
    if (lane < nb) bsum[lane] = v - orig;
}

__global__ __launch_bounds__(256) void scan3_kernel(
    const int* __restrict__ excl, const int* __restrict__ bsum,
    int* __restrict__ rp, int n, int n_edges)
{
    int i = blockIdx.x * 256 + threadIdx.x;
    if (i < n) rp[i] = excl[i] + bsum[i / SCAN_CHUNK];
    if (i == 0) rp[n] = n_edges;
}

// pass 2: atomic-free scatter of src into CSR slots
__global__ __launch_bounds__(256) void fill2_kernel(
    const int* __restrict__ src, const int* __restrict__ dst,
    const int* __restrict__ rp, const int* __restrict__ loc,
    int* __restrict__ csr, int n_edges)
{
    int t = blockIdx.x * 256 + threadIdx.x;
    int e4 = t * 4;
    if (e4 + 4 <= n_edges) {
        int4 d = *reinterpret_cast<const int4*>(dst + e4);
        int4 s = *reinterpret_cast<const int4*>(src + e4);
        int4 l = *reinterpret_cast<const int4*>(loc + e4);
        csr[rp[d.x] + l.x] = s.x;
        csr[rp[d.y] + l.y] = s.y;
        csr[rp[d.z] + l.z] = s.z;
        csr[rp[d.w] + l.w] = s.w;
    } else {
        for (int e = e4; e < n_edges; ++e)
            csr[rp[dst[e]] + loc[e]] = src[e];
    }
}

// ------- fused shift+tap: agg = S xin ; y += agg @ Wk^T + bk ---------------
__global__ __launch_bounds__(256) void pull_tap_kernel(
    const float* __restrict__ xin, float* __restrict__ xagg,
    float* __restrict__ y,
    const int* __restrict__ rp, const int* __restrict__ csr,
    const float* __restrict__ Wk, const float* __restrict__ bk,
    int n_nodes, int write_agg)
{
    __shared__ float Wt[D * (D + 1)];
    __shared__ float bs[D];

    int tid = threadIdx.x;
    for (int t = tid; t < D * D; t += 256) {
        int j = t >> 6, i = t & 63;
        Wt[i * (D + 1) + j] = Wk[t];
    }
    if (tid < D) bs[tid] = bk[tid];
    __syncthreads();

    int node = (blockIdx.x * 256 + tid) >> 6;
    int lane = tid & 63;
    if (node >= n_nodes) return;

    int beg = rp[node], end = rp[node + 1];
    float acc = 0.f;
    for (int e = beg; e < end; e += 64) {
        int cnt = end - e;
        if (cnt > 64) cnt = 64;
        int idx = (lane < cnt) ? csr[e + lane] : 0;
        int i = 0;
        for (; i + 8 <= cnt; i += 8) {
            int s0 = __shfl(idx, i);
            int s1 = __shfl(idx, i + 1);
            int s2 = __shfl(idx, i + 2);
            int s3 = __shfl(idx, i + 3);
            int s4 = __shfl(idx, i + 4);
            int s5 = __shfl(idx, i + 5);
            int s6 = __shfl(idx, i + 6);
            int s7 = __shfl(idx, i + 7);
            float a0 = xin[(size_t)s0 * D + lane];
            float a1 = xin[(size_t)s1 * D + lane];
            float a2 = xin[(size_t)s2 * D + lane];
            float a3 = xin[(size_t)s3 * D + lane];
            float a4 = xin[(size_t)s4 * D + lane];
            float a5 = xin[(size_t)s5 * D + lane];
            float a6 = xin[(size_t)s6 * D + lane];
            float a7 = xin[(size_t)s7 * D + lane];
            acc += (((a0 + a1) + (a2 + a3)) + ((a4 + a5) + (a6 + a7)));
        }
        for (; i < cnt; ++i) {
            int s = __shfl(idx, i);
            acc += xin[(size_t)s * D + lane];
        }
    }

    if (write_agg)
        xagg[(size_t)node * D + lane] = acc;

    // y[node][lane] += sum_i acc_i * W[lane][i] + b[lane]
    float out = bs[lane];
    #pragma unroll
    for (int i = 0; i < D; ++i) {
        float xi = __shfl(acc, i);
        out = fmaf(xi, Wt[i * (D + 1) + lane], out);
    }
    y[(size_t)node * D + lane] += out;
}

// ---------------- fallback (atomic push) if ws too small -------------------
__global__ __launch_bounds__(256) void scatter_kernel(
    const float* __restrict__ xin, float* __restrict__ xout,
    const int* __restrict__ src, const int* __restrict__ dst, int n_edges)
{
    int t = blockIdx.x * blockDim.x + threadIdx.x;
    int e = t >> 4;
    if (e >= n_edges) return;
    int c = (t & 15) * 4;
    int s = src[e];
    int d = dst[e];
    const float4 v = *reinterpret_cast<const float4*>(xin + (size_t)s * D + c);
    float* o = xout + (size_t)d * D + c;
    atomicAdd(o + 0, v.x);
    atomicAdd(o + 1, v.y);
    atomicAdd(o + 2, v.z);
    atomicAdd(o + 3, v.w);
}

extern "C" void kernel_launch(void* const* d_in, const int* in_sizes, int n_in,
                              void* d_out, int out_size, void* d_ws, size_t ws_size,
                              hipStream_t stream) {
    const float* x  = (const float*)d_in[0];
    const int*   ei = (const int*)d_in[1];
    const float* W  = (const float*)d_in[2];
    const float* b  = (const float*)d_in[3];
    float* y = (float*)d_out;

    int n_nodes = in_sizes[0] / D;   // 50000
    int n_edges = in_sizes[1] / 2;   // 800000
    const int* src = ei;
    const int* dst = ei + n_edges;

    int n_pad = ((n_nodes + SCAN_CHUNK - 1) / SCAN_CHUNK) * SCAN_CHUNK; // 50176
    int nblk  = n_pad / SCAN_CHUNK;                                      // 49

    size_t bufElems = (size_t)n_nodes * D;
    float* A = (float*)d_ws;
    float* B = A + bufElems;
    int* counts = (int*)(B + bufElems);
    int* excl   = counts + n_pad;
    int* rp     = excl + n_pad;        // n_nodes+1 used
    int* bsum   = rp + n_pad;          // 64
    int* loc    = bsum + 64;           // n_edges
    int* csr    = loc + n_edges;       // n_edges

    size_t needed = (char*)(csr + n_edges) - (char*)d_ws;

    dim3 tb(256);
    dim3 tg((n_nodes + 3) / 4);
    int e4grid = (n_edges / 4 + 255) / 256;
    int ngrid  = (n_nodes + 255) / 256;
    int pgrid  = (n_nodes * 64 + 255) / 256;

    if (needed <= ws_size) {
        // ---- CSR build (counting sort, single atomic pass) ----
        hipMemsetAsync(counts, 0, (size_t)n_pad * sizeof(int), stream);
        hist_loc_kernel<<<e4grid, tb, 0, stream>>>(dst, counts, loc, n_edges);
        scan1_kernel<<<nblk, tb, 0, stream>>>(counts, excl, bsum, n_nodes);
        scan2_kernel<<<1, 64, 0, stream>>>(bsum, nblk);
        scan3_kernel<<<ngrid, tb, 0, stream>>>(excl, bsum, rp, n_nodes, n_edges);
        fill2_kernel<<<e4grid, tb, 0, stream>>>(src, dst, rp, loc, csr, n_edges);

        // ---- tap 0 + fused shift/tap chain ----
        tap_kernel<<<tg, tb, 0, stream>>>(x, W, b, y, n_nodes, 1);
        pull_tap_kernel<<<pgrid, tb, 0, stream>>>(x, A, y, rp, csr,
                                                  W + 1 * D * D, b + 1 * D, n_nodes, 1);
        pull_tap_kernel<<<pgrid, tb, 0, stream>>>(A, B, y, rp, csr,
                                                  W + 2 * D * D, b + 2 * D, n_nodes, 1);
        pull_tap_kernel<<<pgrid, tb, 0, stream>>>(B, A, y, rp, csr,
                                                  W + 3 * D * D, b + 3 * D, n_nodes, 0);
    } else {
        // ---- fallback: atomic push path ----
        size_t bufBytes = bufElems * sizeof(float);
        int sgrid = (n_edges * 16 + 255) / 256;
        hipMemsetAsync(A, 0, bufBytes, stream);
        hipMemsetAsync(B, 0, bufBytes, stream);
        tap_kernel<<<tg, tb, 0, stream>>>(x, W, b, y, n_nodes, 1);
        scatter_kernel<<<sgrid, tb, 0, stream>>>(x, A, src, dst, n_edges);
        tap_kernel<<<tg, tb, 0, stream>>>(A, W + D * D, b + D, y, n_nodes, 0);
        scatter_kernel<<<sgrid, tb, 0, stream>>>(A, B, src, dst, n_edges);
        hipMemsetAsync(A, 0, bufBytes, stream);
        tap_kernel<<<tg, tb, 0, stream>>>(B, W + 2 * D * D, b + 2 * D, y, n_nodes, 0);
        scatter_kernel<<<sgrid, tb, 0, stream>>>(B, A, src, dst, n_edges);
        tap_kernel<<<tg, tb, 0, stream>>>(A, W + 3 * D * D, b + 3 * D, y, n_nodes, 0);
    }
}